// Round 1
// baseline (213.022 us; speedup 1.0000x reference)
//
#include <hip/hip_runtime.h>

#define NB       65536
#define FEAT     261      // 5 + 4*64
#define HID      128
#define TM       32       // rows per block
#define KC       32       // k-chunk
#define NTHREADS 256

__global__ __launch_bounds__(NTHREADS, 2) void ac_fused(
    const float* __restrict__ x,
    const float* __restrict__ w0, const float* __restrict__ b0,
    const float* __restrict__ w1, const float* __restrict__ b1,
    const float* __restrict__ w2, const float* __restrict__ b2,
    const float* __restrict__ leaf,
    const float* __restrict__ Wc1, const float* __restrict__ bc1,
    const float* __restrict__ Wc2, const float* __restrict__ bc2,
    float* __restrict__ out_p, float* __restrict__ out_v)
{
    __shared__ __align__(16) float xs[TM * FEAT];   // 33408 B, odd stride -> conflict-free cols
    __shared__ __align__(16) float wt[KC * HID];    // 16384 B
    __shared__ __align__(16) float aT[KC * TM];     //  4096 B
    __shared__ float wc2s[HID];
    __shared__ float bc1s[HID];

    const int tid = threadIdx.x;
    const int rowBase = blockIdx.x * TM;

    // ---- stage x tile (contiguous identity copy, float4) + small vectors ----
    {
        const float4* xg = (const float4*)(x + (size_t)rowBase * FEAT);
        float4* xs4 = (float4*)xs;
        for (int i = tid; i < TM * FEAT / 4; i += NTHREADS) xs4[i] = xg[i];
        if (tid < HID) { wc2s[tid] = Wc2[tid]; bc1s[tid] = bc1[tid]; }
    }
    __syncthreads();

    // ---------------- tree phase (fp32, 8 lanes per row) ----------------
    {
        const int s    = tid & 7;
        const int rloc = tid >> 3;
        const float* xr = xs + rloc * FEAT;

        // level 0: full 261-dot with w0 (covers x5 + all 256 dev)
        float part = 0.f;
        for (int k = s; k < FEAT; k += 8) part += xr[k] * w0[k];
        part += __shfl_xor(part, 1);
        part += __shfl_xor(part, 2);
        part += __shfl_xor(part, 4);
        float gate = part + b0[0];
        int node = (gate >= 0.f) ? 1 : 0;
        float cum = 1.f / (1.f + __expf(-gate));

        // level 1: 5 + 128 selected dev floats
        {
            const float* w1r = w1 + node * 133;
            part = (s < 5) ? xr[s] * w1r[s] : 0.f;
            const float* dsl = xr + 5 + node * 128;
            for (int t = s; t < 128; t += 8) part += dsl[t] * w1r[5 + t];
            part += __shfl_xor(part, 1);
            part += __shfl_xor(part, 2);
            part += __shfl_xor(part, 4);
            gate = part + b1[node];
            cum *= 1.f / (1.f + __expf(-gate));
            node = node * 2 + ((gate >= 0.f) ? 1 : 0);
        }
        // level 2: 5 + 64 selected dev floats
        {
            const float* w2r = w2 + node * 69;
            part = (s < 5) ? xr[s] * w2r[s] : 0.f;
            const float* dsl = xr + 5 + node * 64;
            for (int t = s; t < 64; t += 8) part += dsl[t] * w2r[5 + t];
            part += __shfl_xor(part, 1);
            part += __shfl_xor(part, 2);
            part += __shfl_xor(part, 4);
            gate = part + b2[node];
            cum *= 1.f / (1.f + __expf(-gate));
            node = node * 2 + ((gate >= 0.f) ? 1 : 0);
        }
        // p[row][s] = cum * leaf[node][s]; all 8 lanes hold identical cum/node
        out_p[(size_t)(rowBase + rloc) * 8 + s] = cum * leaf[node * 8 + s];
    }

    // ---------------- critic GEMM phase (fp32, 4x4 micro-tile) ----------------
    const int ng = tid & 31;   // n-columns ng*4 .. ng*4+3
    const int rg = tid >> 5;   // rows rg*4 .. rg*4+3
    float acc00=0,acc01=0,acc02=0,acc03=0;
    float acc10=0,acc11=0,acc12=0,acc13=0;
    float acc20=0,acc21=0,acc22=0,acc23=0;
    float acc30=0,acc31=0,acc32=0,acc33=0;

    for (int k0 = 0; k0 < FEAT; k0 += KC) {
        const int klen = (FEAT - k0 < KC) ? (FEAT - k0) : KC;
        __syncthreads();   // previous chunk's reads done before restage
        // stage Wc1 chunk (contiguous identity copy)
        {
            const float4* wg = (const float4*)(Wc1 + (size_t)k0 * HID);
            float4* wt4 = (float4*)wt;
            const int n4 = klen * HID / 4;
            for (int i = tid; i < n4; i += NTHREADS) wt4[i] = wg[i];
        }
        // stage transposed x chunk: aT[kk][r] = xs[r][k0+kk]
        for (int i = tid; i < klen * TM; i += NTHREADS) {
            const int kk = i >> 5;
            const int r  = i & 31;
            aT[kk * TM + r] = xs[r * FEAT + k0 + kk];
        }
        __syncthreads();

        #pragma unroll 4
        for (int kk = 0; kk < klen; ++kk) {
            const float4 av = *(const float4*)&aT[kk * TM + rg * 4];
            const float4 bv = *(const float4*)&wt[kk * HID + ng * 4];
            acc00 += av.x * bv.x; acc01 += av.x * bv.y; acc02 += av.x * bv.z; acc03 += av.x * bv.w;
            acc10 += av.y * bv.x; acc11 += av.y * bv.y; acc12 += av.y * bv.z; acc13 += av.y * bv.w;
            acc20 += av.z * bv.x; acc21 += av.z * bv.y; acc22 += av.z * bv.z; acc23 += av.z * bv.w;
            acc30 += av.w * bv.x; acc31 += av.w * bv.y; acc32 += av.w * bv.z; acc33 += av.w * bv.w;
        }
    }

    // epilogue: bias + relu + dot(Wc2) + reduce across the 32 n-threads
    {
        const int n0 = ng * 4;
        float pv0 = 0.f, pv1 = 0.f, pv2 = 0.f, pv3 = 0.f;
        #pragma unroll
        for (int j = 0; j < 4; ++j) {
            const float bb = bc1s[n0 + j];
            const float ww = wc2s[n0 + j];
            float h;
            h = ((j==0)?acc00:(j==1)?acc01:(j==2)?acc02:acc03) + bb; pv0 += (h > 0.f ? h : 0.f) * ww;
            h = ((j==0)?acc10:(j==1)?acc11:(j==2)?acc12:acc13) + bb; pv1 += (h > 0.f ? h : 0.f) * ww;
            h = ((j==0)?acc20:(j==1)?acc21:(j==2)?acc22:acc23) + bb; pv2 += (h > 0.f ? h : 0.f) * ww;
            h = ((j==0)?acc30:(j==1)?acc31:(j==2)?acc32:acc33) + bb; pv3 += (h > 0.f ? h : 0.f) * ww;
        }
        #pragma unroll
        for (int m = 16; m >= 1; m >>= 1) {
            pv0 += __shfl_xor(pv0, m);
            pv1 += __shfl_xor(pv1, m);
            pv2 += __shfl_xor(pv2, m);
            pv3 += __shfl_xor(pv3, m);
        }
        if (ng == 0) {
            const float bias = bc2[0];
            const int r = rowBase + rg * 4;
            out_v[r + 0] = pv0 + bias;
            out_v[r + 1] = pv1 + bias;
            out_v[r + 2] = pv2 + bias;
            out_v[r + 3] = pv3 + bias;
        }
    }
}

extern "C" void kernel_launch(void* const* d_in, const int* in_sizes, int n_in,
                              void* d_out, int out_size, void* d_ws, size_t ws_size,
                              hipStream_t stream) {
    const float* x    = (const float*)d_in[0];
    const float* w0   = (const float*)d_in[1];
    const float* b0   = (const float*)d_in[2];
    const float* w1   = (const float*)d_in[3];
    const float* b1   = (const float*)d_in[4];
    const float* w2   = (const float*)d_in[5];
    const float* b2   = (const float*)d_in[6];
    const float* leaf = (const float*)d_in[7];
    const float* Wc1  = (const float*)d_in[8];
    const float* bc1  = (const float*)d_in[9];
    const float* Wc2  = (const float*)d_in[10];
    const float* bc2  = (const float*)d_in[11];

    float* out_p = (float*)d_out;
    float* out_v = out_p + (size_t)NB * 8;

    ac_fused<<<NB / TM, NTHREADS, 0, stream>>>(
        x, w0, b0, w1, b1, w2, b2, leaf, Wc1, bc1, Wc2, bc2, out_p, out_v);
}

// Round 2
// 178.901 us; speedup vs baseline: 1.1907x; 1.1907x over previous
//
#include <hip/hip_runtime.h>
#include <hip/hip_bf16.h>
#include <stdint.h>

#define NB    65536
#define FEATN 261
#define HIDN  128
#define ROWS  128          // rows per block
#define KPAD  272          // 17 MFMA steps of K=16
#define NSTEP 17
#define NTHR  256

typedef __attribute__((ext_vector_type(8)))  short bf16x8;   // 8 bf16 = 4 VGPRs
typedef __attribute__((ext_vector_type(16))) float f32x16;   // 32x32 accum

// ---------- pre-kernel: wsB[n][kp] bf16, n-major k-contiguous, zero-padded ----------
__global__ void prep_B(const float* __restrict__ Wc1, uint16_t* __restrict__ wsB) {
    int i = blockIdx.x * blockDim.x + threadIdx.x;
    if (i >= HIDN * KPAD) return;
    int n = i / KPAD, kp = i - n * KPAD;
    float v = (kp < FEATN) ? Wc1[(size_t)kp * HIDN + n] : 0.f;
    __hip_bfloat16 b = __float2bfloat16(v);
    wsB[i] = *reinterpret_cast<uint16_t*>(&b);
}

// ---------- main fused kernel ----------
__global__ __launch_bounds__(NTHR, 2) void ac_fused(
    const float* __restrict__ x,
    const float* __restrict__ w0, const float* __restrict__ b0,
    const float* __restrict__ w1, const float* __restrict__ b1,
    const float* __restrict__ w2, const float* __restrict__ b2,
    const float* __restrict__ leaf,
    const uint16_t* __restrict__ wsB,
    const float* __restrict__ bc1, const float* __restrict__ Wc2,
    const float* __restrict__ bc2,
    float* __restrict__ out_p, float* __restrict__ out_v)
{
    // A-store: frag-ordered bf16. piece(s,mt) = s*4+mt, 1024 B each:
    //   halfword idx = piece*512 + lane*8 + (k&7), lane = ((k>>3)&1)*32 + (m&31)
    __shared__ uint16_t Asm[4 * NSTEP * 512];   // 69632 B
    __shared__ uint16_t Bsm[2 * 4 * 512];       //  8192 B (2 k-steps x 4 n-tiles)
    __shared__ float bc1s[HIDN];
    __shared__ float wc2s[HIDN];
    __shared__ float vpart[ROWS * 2];           // per-row partial v from 2 n-halves

    const int tid = threadIdx.x;
    const int rowBase = blockIdx.x * ROWS;

    if (tid < HIDN) { bc1s[tid] = bc1[tid]; wc2s[tid] = Wc2[tid]; }
    // zero the K-pad region (pieces for s=16): k in [256,272); valid k 256..260
    // overwritten after the barrier by the scatter.
    {
        uint4 z; z.x = z.y = z.z = z.w = 0u;
        *reinterpret_cast<uint4*>(&Asm[64 * 512 + tid * 8]) = z;
    }
    __syncthreads();

    // ---------------- phase 1: per 32-row sub-tile: scatter + tree ----------------
    for (int sub = 0; sub < 4; ++sub) {
        // --- A-scatter: flat float4 over 32x261 fp32 (16B-aligned), bf16 b16 scatter ---
        const float4* xg4 = reinterpret_cast<const float4*>(
            x + (size_t)(rowBase + sub * 32) * FEATN);
        for (int i = tid; i < (32 * FEATN) / 4; i += NTHR) {
            float4 v = xg4[i];
            const float* vv = reinterpret_cast<const float*>(&v);
            int f = i << 2;
            int m = f / FEATN;              // compiler magic-div
            int k = f - m * FEATN;
            int mg = sub * 32 + m;
            if (k + 3 < FEATN) {            // fast path: one row, no 261-crossing
                const int mterm = ((mg >> 5) << 9) + ((mg & 31) << 3);
                #pragma unroll
                for (int j = 0; j < 4; ++j) {
                    __hip_bfloat16 b = __float2bfloat16(vv[j]);
                    int hw = ((k >> 4) << 11) + (((k >> 3) & 1) << 8) + mterm + (k & 7);
                    Asm[hw] = *reinterpret_cast<uint16_t*>(&b);
                    k++;
                }
            } else {
                #pragma unroll
                for (int j = 0; j < 4; ++j) {
                    if (k >= FEATN) { k -= FEATN; mg++; }
                    __hip_bfloat16 b = __float2bfloat16(vv[j]);
                    int hw = ((k >> 4) << 11) + (((k >> 3) & 1) << 8)
                           + ((mg >> 5) << 9) + ((mg & 31) << 3) + (k & 7);
                    Asm[hw] = *reinterpret_cast<uint16_t*>(&b);
                    k++;
                }
            }
        }

        // --- tree (fp32, x from global — lines are L2-hot from the scatter) ---
        #pragma unroll
        for (int pass = 0; pass < 2; ++pass) {
            const int s    = tid & 15;
            const int rloc = sub * 32 + pass * 16 + (tid >> 4);
            const float* xr = x + (size_t)(rowBase + rloc) * FEATN;

            float part = 0.f;
            for (int k = s; k < FEATN; k += 16) part += xr[k] * w0[k];
            part += __shfl_xor(part, 1);
            part += __shfl_xor(part, 2);
            part += __shfl_xor(part, 4);
            part += __shfl_xor(part, 8);
            float gate = part + b0[0];
            int node = (gate >= 0.f) ? 1 : 0;
            float cum = 1.f / (1.f + __expf(-gate));

            {
                const float* w1r = w1 + node * 133;
                part = (s < 5) ? xr[s] * w1r[s] : 0.f;
                const float* dsl = xr + 5 + node * 128;
                for (int t = s; t < 128; t += 16) part += dsl[t] * w1r[5 + t];
                part += __shfl_xor(part, 1);
                part += __shfl_xor(part, 2);
                part += __shfl_xor(part, 4);
                part += __shfl_xor(part, 8);
                gate = part + b1[node];
                cum *= 1.f / (1.f + __expf(-gate));
                node = node * 2 + ((gate >= 0.f) ? 1 : 0);
            }
            {
                const float* w2r = w2 + node * 69;
                part = (s < 5) ? xr[s] * w2r[s] : 0.f;
                const float* dsl = xr + 5 + node * 64;
                for (int t = s; t < 64; t += 16) part += dsl[t] * w2r[5 + t];
                part += __shfl_xor(part, 1);
                part += __shfl_xor(part, 2);
                part += __shfl_xor(part, 4);
                part += __shfl_xor(part, 8);
                gate = part + b2[node];
                cum *= 1.f / (1.f + __expf(-gate));
                node = node * 2 + ((gate >= 0.f) ? 1 : 0);
            }
            if (s < 8)
                out_p[(size_t)(rowBase + rloc) * 8 + s] = cum * leaf[node * 8 + s];
        }
    }
    __syncthreads();

    // ---------------- phase 2: MFMA K-loop ----------------
    const int lane = tid & 63;
    const int w    = tid >> 6;           // wave 0..3
    const int mtb  = (w >> 1) * 2;       // m-tiles {mtb, mtb+1}
    const int ntb  = (w & 1) * 2;        // n-tiles {ntb, ntb+1}

    f32x16 acc00 = {}, acc01 = {}, acc10 = {}, acc11 = {};

    for (int c9 = 0; c9 < 9; ++c9) {
        __syncthreads();                 // readers done with previous B chunk
        #pragma unroll
        for (int i = 0; i < 2; ++i) {    // stage 2 k-steps of B (512 x 16B pieces)
            int p = tid + NTHR * i;
            int d = p >> 8, rem = p & 255, nt = rem >> 6, l = rem & 63;
            int s = 2 * c9 + d;
            if (s < NSTEP) {
                const uint16_t* src = wsB + (size_t)(nt * 32 + (l & 31)) * KPAD
                                    + s * 16 + (l >> 5) * 8;
                *reinterpret_cast<uint4*>(&Bsm[p * 8]) =
                    *reinterpret_cast<const uint4*>(src);
            }
        }
        __syncthreads();

        #pragma unroll
        for (int d = 0; d < 2; ++d) {
            int s = 2 * c9 + d;
            if (s >= NSTEP) break;       // uniform (only c9=8,d=1)
            bf16x8 a0 = *reinterpret_cast<const bf16x8*>(&Asm[(s * 4 + mtb    ) * 512 + lane * 8]);
            bf16x8 a1 = *reinterpret_cast<const bf16x8*>(&Asm[(s * 4 + mtb + 1) * 512 + lane * 8]);
            bf16x8 bv0 = *reinterpret_cast<const bf16x8*>(&Bsm[(d * 4 + ntb    ) * 512 + lane * 8]);
            bf16x8 bv1 = *reinterpret_cast<const bf16x8*>(&Bsm[(d * 4 + ntb + 1) * 512 + lane * 8]);
            acc00 = __builtin_amdgcn_mfma_f32_32x32x16_bf16(a0, bv0, acc00, 0, 0, 0);
            acc01 = __builtin_amdgcn_mfma_f32_32x32x16_bf16(a0, bv1, acc01, 0, 0, 0);
            acc10 = __builtin_amdgcn_mfma_f32_32x32x16_bf16(a1, bv0, acc10, 0, 0, 0);
            acc11 = __builtin_amdgcn_mfma_f32_32x32x16_bf16(a1, bv1, acc11, 0, 0, 0);
        }
    }

    // ---------------- epilogue: bias+relu+Wc2 dot, reduce, write v ----------------
    {
        const int c = lane & 31;         // = local n within n-tile
        const int q = lane >> 5;
        const int n0 = (ntb    ) * 32 + c;
        const int n1 = (ntb + 1) * 32 + c;
        const float bb0 = bc1s[n0], ww0 = wc2s[n0];
        const float bb1 = bc1s[n1], ww1 = wc2s[n1];

        #pragma unroll
        for (int a = 0; a < 2; ++a) {
            const f32x16& A0 = a ? acc10 : acc00;
            const f32x16& A1 = a ? acc11 : acc01;
            float pv[16];
            #pragma unroll
            for (int reg = 0; reg < 16; ++reg) {
                float h0 = A0[reg] + bb0; h0 = h0 > 0.f ? h0 : 0.f;
                float h1 = A1[reg] + bb1; h1 = h1 > 0.f ? h1 : 0.f;
                float t = h0 * ww0 + h1 * ww1;
                t += __shfl_xor(t, 1);
                t += __shfl_xor(t, 2);
                t += __shfl_xor(t, 4);
                t += __shfl_xor(t, 8);
                t += __shfl_xor(t, 16);
                pv[reg] = t;
            }
            #pragma unroll
            for (int reg = 0; reg < 16; ++reg) {
                if (c == reg) {
                    int row_local = (reg & 3) + 8 * (reg >> 2) + 4 * q;
                    int grow = (mtb + a) * 32 + row_local;
                    vpart[grow * 2 + (w & 1)] = pv[reg];
                }
            }
        }
    }
    __syncthreads();
    if (tid < ROWS)
        out_v[rowBase + tid] = vpart[tid * 2] + vpart[tid * 2 + 1] + bc2[0];
}

extern "C" void kernel_launch(void* const* d_in, const int* in_sizes, int n_in,
                              void* d_out, int out_size, void* d_ws, size_t ws_size,
                              hipStream_t stream) {
    const float* x    = (const float*)d_in[0];
    const float* w0   = (const float*)d_in[1];
    const float* b0   = (const float*)d_in[2];
    const float* w1   = (const float*)d_in[3];
    const float* b1   = (const float*)d_in[4];
    const float* w2   = (const float*)d_in[5];
    const float* b2   = (const float*)d_in[6];
    const float* leaf = (const float*)d_in[7];
    const float* Wc1  = (const float*)d_in[8];
    const float* bc1  = (const float*)d_in[9];
    const float* Wc2  = (const float*)d_in[10];
    const float* bc2  = (const float*)d_in[11];

    uint16_t* wsB = (uint16_t*)d_ws;     // 128*272*2 = 69632 B

    float* out_p = (float*)d_out;
    float* out_v = out_p + (size_t)NB * 8;

    prep_B<<<(HIDN * KPAD + 255) / 256, 256, 0, stream>>>(Wc1, wsB);
    ac_fused<<<NB / ROWS, NTHR, 0, stream>>>(
        x, w0, b0, w1, b1, w2, b2, leaf, wsB, bc1, Wc2, bc2, out_p, out_v);
}

// Round 3
// 162.146 us; speedup vs baseline: 1.3138x; 1.1033x over previous
//
#include <hip/hip_runtime.h>
#include <hip/hip_bf16.h>
#include <stdint.h>

#define NB    65536
#define FEATN 261
#define HIDN  128
#define ROWS  64           // rows per block
#define NSTEP 17           // 17 MFMA k-steps of 16
#define SROW  296          // LDS A row stride in halfwords (16B-aligned, 4-way banks)
#define NTHR  256

typedef __attribute__((ext_vector_type(8)))  short bf16x8;   // 8 bf16 = 4 VGPRs
typedef __attribute__((ext_vector_type(16))) float f32x16;   // 32x32 accum

// ---------- pre-kernel: pack Wc1 into MFMA B-fragment order in d_ws ----------
// piece p = s*4 + nt (17*4 pieces, 1024 B each). Within piece, lane l holds 8
// halfwords (16 B): n = nt*32 + (l&31), k = 16s + 8*(l>>5) + j, zero for k>=261.
__global__ void prep_B(const float* __restrict__ Wc1, uint16_t* __restrict__ wsB) {
    int t = blockIdx.x * blockDim.x + threadIdx.x;   // one thread per (p, l)
    if (t >= NSTEP * 4 * 64) return;
    int p = t >> 6, l = t & 63;
    int s = p >> 2, nt = p & 3;
    int n = nt * 32 + (l & 31);
    int kb = 16 * s + 8 * (l >> 5);
    uint16_t hw[8];
    #pragma unroll
    for (int j = 0; j < 8; ++j) {
        int k = kb + j;
        float v = (k < FEATN) ? Wc1[(size_t)k * HIDN + n] : 0.f;
        __hip_bfloat16 b = __float2bfloat16(v);
        hw[j] = *reinterpret_cast<uint16_t*>(&b);
    }
    *reinterpret_cast<uint4*>(wsB + (size_t)p * 512 + l * 8) =
        *reinterpret_cast<uint4*>(hw);
}

// ---------- main fused kernel ----------
__global__ __launch_bounds__(NTHR, 4) void ac_fused(
    const float* __restrict__ x,
    const float* __restrict__ w0, const float* __restrict__ b0,
    const float* __restrict__ w1, const float* __restrict__ b1,
    const float* __restrict__ w2, const float* __restrict__ b2,
    const float* __restrict__ leaf,
    const uint16_t* __restrict__ wsB,
    const float* __restrict__ bc1, const float* __restrict__ Wc2,
    const float* __restrict__ bc2,
    float* __restrict__ out_p, float* __restrict__ out_v)
{
    __shared__ uint16_t Axs[ROWS * SROW];      // 37888 B, row-major bf16, k-contig
    __shared__ float bc1s[HIDN];
    __shared__ float wc2s[HIDN];
    __shared__ float vpart[ROWS * 2];

    const int tid = threadIdx.x;
    const int rowBase = blockIdx.x * ROWS;

    if (tid < HIDN) { bc1s[tid] = bc1[tid]; wc2s[tid] = Wc2[tid]; }
    // zero k = 261..295 pad of each row (disjoint from staging writes)
    if (tid < ROWS) {
        uint16_t* rp = Axs + tid * SROW;
        rp[261] = 0;
        *reinterpret_cast<uint32_t*>(rp + 262) = 0u;
        uint4 z; z.x = z.y = z.z = z.w = 0u;
        *reinterpret_cast<uint4*>(rp + 264) = z;
        *reinterpret_cast<uint4*>(rp + 272) = z;
        *reinterpret_cast<uint4*>(rp + 280) = z;
        *reinterpret_cast<uint4*>(rp + 288) = z;
    }

    // ---- phase 1a: coalesced float4 x read -> bf16 -> row-major LDS ----
    {
        const float4* xg4 = reinterpret_cast<const float4*>(x + (size_t)rowBase * FEATN);
        for (int i = tid; i < ROWS * FEATN / 4; i += NTHR) {
            float4 v = xg4[i];
            const float* vv = reinterpret_cast<const float*>(&v);
            int f = i << 2;
            int m = f / FEATN;          // magic-div
            int k = f - m * FEATN;
            if (k + 3 < FEATN) {        // fast path: single row
                uint16_t* dst = Axs + m * SROW + k;
                #pragma unroll
                for (int j = 0; j < 4; ++j) {
                    __hip_bfloat16 b = __float2bfloat16(vv[j]);
                    dst[j] = *reinterpret_cast<uint16_t*>(&b);
                }
            } else {
                #pragma unroll
                for (int j = 0; j < 4; ++j) {
                    if (k >= FEATN) { k -= FEATN; m++; }
                    __hip_bfloat16 b = __float2bfloat16(vv[j]);
                    Axs[m * SROW + k] = *reinterpret_cast<uint16_t*>(&b);
                    k++;
                }
            }
        }
    }

    // ---- phase 1b: tree (fp32 from global; lines are L2/L1-hot) ----
    #pragma unroll
    for (int pass = 0; pass < 4; ++pass) {
        const int s    = tid & 15;
        const int rloc = pass * 16 + (tid >> 4);
        const float* xr = x + (size_t)(rowBase + rloc) * FEATN;

        float part = 0.f;
        for (int k = s; k < FEATN; k += 16) part += xr[k] * w0[k];
        part += __shfl_xor(part, 1);
        part += __shfl_xor(part, 2);
        part += __shfl_xor(part, 4);
        part += __shfl_xor(part, 8);
        float gate = part + b0[0];
        int node = (gate >= 0.f) ? 1 : 0;
        float cum = 1.f / (1.f + __expf(-gate));
        {
            const float* w1r = w1 + node * 133;
            part = (s < 5) ? xr[s] * w1r[s] : 0.f;
            const float* dsl = xr + 5 + node * 128;
            for (int t = s; t < 128; t += 16) part += dsl[t] * w1r[5 + t];
            part += __shfl_xor(part, 1);
            part += __shfl_xor(part, 2);
            part += __shfl_xor(part, 4);
            part += __shfl_xor(part, 8);
            gate = part + b1[node];
            cum *= 1.f / (1.f + __expf(-gate));
            node = node * 2 + ((gate >= 0.f) ? 1 : 0);
        }
        {
            const float* w2r = w2 + node * 69;
            part = (s < 5) ? xr[s] * w2r[s] : 0.f;
            const float* dsl = xr + 5 + node * 64;
            for (int t = s; t < 64; t += 16) part += dsl[t] * w2r[5 + t];
            part += __shfl_xor(part, 1);
            part += __shfl_xor(part, 2);
            part += __shfl_xor(part, 4);
            part += __shfl_xor(part, 8);
            gate = part + b2[node];
            cum *= 1.f / (1.f + __expf(-gate));
            node = node * 2 + ((gate >= 0.f) ? 1 : 0);
        }
        if (s < 8)
            out_p[(size_t)(rowBase + rloc) * 8 + s] = cum * leaf[node * 8 + s];
    }

    __syncthreads();   // the only barrier before the K-loop

    // ---- phase 2: MFMA K-loop; A from LDS (b128), B from global frag-order ----
    const int lane = tid & 63;
    const int w    = tid >> 6;
    const int mt   = w >> 1;            // m-tile 0/1
    const int nh   = w & 1;             // n-tiles {2nh, 2nh+1}

    f32x16 acc0 = {}, acc1 = {};
    const uint16_t* arow = Axs + (mt * 32 + (lane & 31)) * SROW + (lane >> 5) * 8;
    const uint16_t* bgl  = wsB + (size_t)(2 * nh) * 512 + lane * 8;

    #pragma unroll
    for (int s = 0; s < NSTEP; ++s) {
        bf16x8 a  = *reinterpret_cast<const bf16x8*>(arow + s * 16);
        bf16x8 b0f = *reinterpret_cast<const bf16x8*>(bgl + (size_t)(s * 4) * 512);
        bf16x8 b1f = *reinterpret_cast<const bf16x8*>(bgl + (size_t)(s * 4 + 1) * 512);
        acc0 = __builtin_amdgcn_mfma_f32_32x32x16_bf16(a, b0f, acc0, 0, 0, 0);
        acc1 = __builtin_amdgcn_mfma_f32_32x32x16_bf16(a, b1f, acc1, 0, 0, 0);
    }

    // ---- epilogue: bias+relu+Wc2 dot, cross-lane reduce, v write ----
    {
        const int c = lane & 31;
        const int q = lane >> 5;
        const int n0 = 2 * nh * 32 + c;
        const int n1 = n0 + 32;
        const float bb0 = bc1s[n0], ww0 = wc2s[n0];
        const float bb1 = bc1s[n1], ww1 = wc2s[n1];

        float pv[16];
        #pragma unroll
        for (int reg = 0; reg < 16; ++reg) {
            float h0 = acc0[reg] + bb0; h0 = h0 > 0.f ? h0 : 0.f;
            float h1 = acc1[reg] + bb1; h1 = h1 > 0.f ? h1 : 0.f;
            float t = h0 * ww0 + h1 * ww1;
            t += __shfl_xor(t, 1);
            t += __shfl_xor(t, 2);
            t += __shfl_xor(t, 4);
            t += __shfl_xor(t, 8);
            t += __shfl_xor(t, 16);
            pv[reg] = t;
        }
        #pragma unroll
        for (int reg = 0; reg < 16; ++reg) {
            if (c == reg) {
                int row_local = (reg & 3) + 8 * (reg >> 2) + 4 * q;
                vpart[(mt * 32 + row_local) * 2 + nh] = pv[reg];
            }
        }
    }
    __syncthreads();
    if (tid < ROWS)
        out_v[rowBase + tid] = vpart[tid * 2] + vpart[tid * 2 + 1] + bc2[0];
}

extern "C" void kernel_launch(void* const* d_in, const int* in_sizes, int n_in,
                              void* d_out, int out_size, void* d_ws, size_t ws_size,
                              hipStream_t stream) {
    const float* x    = (const float*)d_in[0];
    const float* w0   = (const float*)d_in[1];
    const float* b0   = (const float*)d_in[2];
    const float* w1   = (const float*)d_in[3];
    const float* b1   = (const float*)d_in[4];
    const float* w2   = (const float*)d_in[5];
    const float* b2   = (const float*)d_in[6];
    const float* leaf = (const float*)d_in[7];
    const float* Wc1  = (const float*)d_in[8];
    const float* bc1  = (const float*)d_in[9];
    const float* Wc2  = (const float*)d_in[10];
    const float* bc2  = (const float*)d_in[11];

    uint16_t* wsB = (uint16_t*)d_ws;     // 17*4*1024 = 69632 B, frag order

    float* out_p = (float*)d_out;
    float* out_v = out_p + (size_t)NB * 8;

    prep_B<<<(NSTEP * 4 * 64 + 255) / 256, 256, 0, stream>>>(Wc1, wsB);
    ac_fused<<<NB / ROWS, NTHR, 0, stream>>>(
        x, w0, b0, w1, b1, w2, b2, leaf, wsB, bc1, Wc2, bc2, out_p, out_v);
}

// Round 4
// 141.630 us; speedup vs baseline: 1.5041x; 1.1449x over previous
//
#include <hip/hip_runtime.h>
#include <hip/hip_bf16.h>
#include <stdint.h>

#define NB    65536
#define FEATN 261
#define HIDN  128
#define ROWS  64           // rows per block
#define NSTEP 17           // 17 MFMA k-steps of 16
#define SROW  296          // LDS A row stride in halfwords (16B-aligned)
#define NTHR  256

typedef __attribute__((ext_vector_type(8)))  short bf16x8;   // 8 bf16 = 4 VGPRs
typedef __attribute__((ext_vector_type(16))) float f32x16;   // 32x32 accum

#define MFMA32(A, B, C) __builtin_amdgcn_mfma_f32_32x32x16_bf16(A, B, C, 0, 0, 0)

// ---------- pre-kernel: pack Wc1 into MFMA B-fragment order in d_ws ----------
// piece p = s*4 + nt (17*4 pieces, 1024 B each). lane l: n = nt*32 + (l&31),
// k = 16s + 8*(l>>5) + j, zero-padded past k=260.
__global__ void prep_B(const float* __restrict__ Wc1, uint16_t* __restrict__ wsB) {
    int t = blockIdx.x * blockDim.x + threadIdx.x;
    if (t >= NSTEP * 4 * 64) return;
    int p = t >> 6, l = t & 63;
    int s = p >> 2, nt = p & 3;
    int n = nt * 32 + (l & 31);
    int kb = 16 * s + 8 * (l >> 5);
    uint16_t hw[8];
    #pragma unroll
    for (int j = 0; j < 8; ++j) {
        int k = kb + j;
        float v = (k < FEATN) ? Wc1[(size_t)k * HIDN + n] : 0.f;
        __hip_bfloat16 b = __float2bfloat16(v);
        hw[j] = *reinterpret_cast<uint16_t*>(&b);
    }
    *reinterpret_cast<uint4*>(wsB + (size_t)p * 512 + l * 8) =
        *reinterpret_cast<uint4*>(hw);
}

// ---------- main fused kernel ----------
__global__ __launch_bounds__(NTHR, 4) void ac_fused(
    const float* __restrict__ x,
    const float* __restrict__ w0, const float* __restrict__ b0,
    const float* __restrict__ w1, const float* __restrict__ b1,
    const float* __restrict__ w2, const float* __restrict__ b2,
    const float* __restrict__ leaf,
    const uint16_t* __restrict__ wsB,
    const float* __restrict__ bc1, const float* __restrict__ Wc2,
    const float* __restrict__ bc2,
    float* __restrict__ out_p, float* __restrict__ out_v)
{
    __shared__ uint16_t Axs[ROWS * SROW];      // 37888 B, row-major bf16, k-contig
    __shared__ float bc1s[HIDN];
    __shared__ float wc2s[HIDN];
    __shared__ float vpart[ROWS * 2];

    const int tid = threadIdx.x;
    const int rowBase = blockIdx.x * ROWS;

    if (tid < HIDN) { bc1s[tid] = bc1[tid]; wc2s[tid] = Wc2[tid]; }
    // zero the k = 261..295 pad of each row
    if (tid < ROWS) {
        uint16_t* rp = Axs + tid * SROW;
        rp[261] = 0;
        *reinterpret_cast<uint32_t*>(rp + 262) = 0u;
        uint4 z; z.x = z.y = z.z = z.w = 0u;
        *reinterpret_cast<uint4*>(rp + 264) = z;
        *reinterpret_cast<uint4*>(rp + 272) = z;
        *reinterpret_cast<uint4*>(rp + 280) = z;
        *reinterpret_cast<uint4*>(rp + 288) = z;
    }

    // ---- phase 1a: coalesced float4 x read -> bf16 -> row-major LDS ----
    {
        const float4* xg4 = reinterpret_cast<const float4*>(x + (size_t)rowBase * FEATN);
        for (int i = tid; i < ROWS * FEATN / 4; i += NTHR) {
            float4 v = xg4[i];
            const float* vv = reinterpret_cast<const float*>(&v);
            int f = i << 2;
            int m = f / FEATN;          // magic-div
            int k = f - m * FEATN;
            if (k + 3 < FEATN) {        // fast path: single row
                uint16_t* dst = Axs + m * SROW + k;
                #pragma unroll
                for (int j = 0; j < 4; ++j) {
                    __hip_bfloat16 b = __float2bfloat16(vv[j]);
                    dst[j] = *reinterpret_cast<uint16_t*>(&b);
                }
            } else {
                #pragma unroll
                for (int j = 0; j < 4; ++j) {
                    if (k >= FEATN) { k -= FEATN; m++; }
                    __hip_bfloat16 b = __float2bfloat16(vv[j]);
                    Axs[m * SROW + k] = *reinterpret_cast<uint16_t*>(&b);
                    k++;
                }
            }
        }
    }

    // ---- phase 1b: tree (fp32 from global, L2-hot). Uniform trip counts +
    //      exec-masked tails so every level's loads issue as one batch. ----
    #pragma unroll
    for (int pass = 0; pass < 4; ++pass) {
        const int s    = tid & 15;
        const int rloc = pass * 16 + (tid >> 4);
        const float* xr = x + (size_t)(rowBase + rloc) * FEATN;

        // level 0: 17 masked iterations, fully unrolled -> 17 loads in flight
        float part = 0.f;
        #pragma unroll
        for (int j = 0; j < 17; ++j) {
            int k = s + 16 * j;
            if (k < FEATN) part += xr[k] * w0[k];
        }
        part += __shfl_xor(part, 1);
        part += __shfl_xor(part, 2);
        part += __shfl_xor(part, 4);
        part += __shfl_xor(part, 8);
        float gate = part + b0[0];
        int node = (gate >= 0.f) ? 1 : 0;
        float cum = 1.f / (1.f + __expf(-gate));

        // level 1: 133 terms, 9 masked iterations
        {
            const float* w1r = w1 + node * 133;
            const float* dsl = xr + node * 128;   // dev idx t-5 -> xr[5+node*128+t-5]
            part = (s < 5) ? xr[s] * w1r[s] : dsl[s] * w1r[s];
            #pragma unroll
            for (int j = 1; j < 9; ++j) {
                int t = s + 16 * j;
                if (t < 133) part += dsl[t] * w1r[t];
            }
            part += __shfl_xor(part, 1);
            part += __shfl_xor(part, 2);
            part += __shfl_xor(part, 4);
            part += __shfl_xor(part, 8);
            gate = part + b1[node];
            cum *= 1.f / (1.f + __expf(-gate));
            node = node * 2 + ((gate >= 0.f) ? 1 : 0);
        }
        // level 2: 69 terms, 5 masked iterations
        {
            const float* w2r = w2 + node * 69;
            const float* dsl = xr + node * 64;
            part = (s < 5) ? xr[s] * w2r[s] : dsl[s] * w2r[s];
            #pragma unroll
            for (int j = 1; j < 5; ++j) {
                int t = s + 16 * j;
                if (t < 69) part += dsl[t] * w2r[t];
            }
            part += __shfl_xor(part, 1);
            part += __shfl_xor(part, 2);
            part += __shfl_xor(part, 4);
            part += __shfl_xor(part, 8);
            gate = part + b2[node];
            cum *= 1.f / (1.f + __expf(-gate));
            node = node * 2 + ((gate >= 0.f) ? 1 : 0);
        }
        if (s < 8)
            out_p[(size_t)(rowBase + rloc) * 8 + s] = cum * leaf[node * 8 + s];
    }

    __syncthreads();   // the only barrier before the K-loop

    // ---- phase 2: MFMA K-loop. A from LDS (b128), B from global frag-order.
    //      Groups of 4 steps: 12 frag loads batched, then 8 MFMAs; two
    //      independent acc pairs (even/odd group) break the MFMA dep chain. ----
    const int lane = tid & 63;
    const int w    = tid >> 6;
    const int mt   = w >> 1;            // m-tile 0/1
    const int nh   = w & 1;             // n-tiles {2nh, 2nh+1}

    f32x16 accE0 = {}, accE1 = {}, accO0 = {}, accO1 = {};
    const uint16_t* arow = Axs + (mt * 32 + (lane & 31)) * SROW + (lane >> 5) * 8;
    const uint16_t* bgl  = wsB + (size_t)(2 * nh) * 512 + lane * 8;

    #pragma unroll
    for (int g = 0; g < 4; ++g) {
        bf16x8 a[4], f0[4], f1[4];
        #pragma unroll
        for (int d = 0; d < 4; ++d) {
            const int s = g * 4 + d;
            a[d]  = *reinterpret_cast<const bf16x8*>(arow + s * 16);
            f0[d] = *reinterpret_cast<const bf16x8*>(bgl + (size_t)(s * 4)     * 512);
            f1[d] = *reinterpret_cast<const bf16x8*>(bgl + (size_t)(s * 4 + 1) * 512);
        }
        #pragma unroll
        for (int d = 0; d < 4; ++d) {
            if ((d & 1) == 0) {
                accE0 = MFMA32(a[d], f0[d], accE0);
                accE1 = MFMA32(a[d], f1[d], accE1);
            } else {
                accO0 = MFMA32(a[d], f0[d], accO0);
                accO1 = MFMA32(a[d], f1[d], accO1);
            }
        }
    }
    {   // tail step s = 16
        bf16x8 a  = *reinterpret_cast<const bf16x8*>(arow + 16 * 16);
        bf16x8 f0 = *reinterpret_cast<const bf16x8*>(bgl + (size_t)(16 * 4)     * 512);
        bf16x8 f1 = *reinterpret_cast<const bf16x8*>(bgl + (size_t)(16 * 4 + 1) * 512);
        accE0 = MFMA32(a, f0, accE0);
        accE1 = MFMA32(a, f1, accE1);
    }

    // ---- epilogue: bias+relu+Wc2 dot, cross-lane reduce, v write ----
    {
        const int c = lane & 31;
        const int q = lane >> 5;
        const int n0 = 2 * nh * 32 + c;
        const int n1 = n0 + 32;
        const float bb0 = bc1s[n0], ww0 = wc2s[n0];
        const float bb1 = bc1s[n1], ww1 = wc2s[n1];

        float pv[16];
        #pragma unroll
        for (int reg = 0; reg < 16; ++reg) {
            float h0 = (accE0[reg] + accO0[reg]) + bb0; h0 = h0 > 0.f ? h0 : 0.f;
            float h1 = (accE1[reg] + accO1[reg]) + bb1; h1 = h1 > 0.f ? h1 : 0.f;
            float t = h0 * ww0 + h1 * ww1;
            t += __shfl_xor(t, 1);
            t += __shfl_xor(t, 2);
            t += __shfl_xor(t, 4);
            t += __shfl_xor(t, 8);
            t += __shfl_xor(t, 16);
            pv[reg] = t;
        }
        #pragma unroll
        for (int reg = 0; reg < 16; ++reg) {
            if (c == reg) {
                int row_local = (reg & 3) + 8 * (reg >> 2) + 4 * q;
                vpart[(mt * 32 + row_local) * 2 + nh] = pv[reg];
            }
        }
    }
    __syncthreads();
    if (tid < ROWS)
        out_v[rowBase + tid] = vpart[tid * 2] + vpart[tid * 2 + 1] + bc2[0];
}

extern "C" void kernel_launch(void* const* d_in, const int* in_sizes, int n_in,
                              void* d_out, int out_size, void* d_ws, size_t ws_size,
                              hipStream_t stream) {
    const float* x    = (const float*)d_in[0];
    const float* w0   = (const float*)d_in[1];
    const float* b0   = (const float*)d_in[2];
    const float* w1   = (const float*)d_in[3];
    const float* b1   = (const float*)d_in[4];
    const float* w2   = (const float*)d_in[5];
    const float* b2   = (const float*)d_in[6];
    const float* leaf = (const float*)d_in[7];
    const float* Wc1  = (const float*)d_in[8];
    const float* bc1  = (const float*)d_in[9];
    const float* Wc2  = (const float*)d_in[10];
    const float* bc2  = (const float*)d_in[11];

    uint16_t* wsB = (uint16_t*)d_ws;     // 17*4*1024 = 69632 B, frag order

    float* out_p = (float*)d_out;
    float* out_v = out_p + (size_t)NB * 8;

    prep_B<<<(NSTEP * 4 * 64 + 255) / 256, 256, 0, stream>>>(Wc1, wsB);
    ac_fused<<<NB / ROWS, NTHR, 0, stream>>>(
        x, w0, b0, w1, b1, w2, b2, leaf, wsB, bc1, Wc2, bc2, out_p, out_v);
}

// Round 5
// 140.950 us; speedup vs baseline: 1.5113x; 1.0048x over previous
//
#include <hip/hip_runtime.h>
#include <hip/hip_bf16.h>
#include <stdint.h>

#define NB    65536
#define FEATN 261
#define HIDN  128
#define ROWS  64           // rows per block
#define NSTEP 17           // 17 MFMA k-steps of 16
#define SROW  296          // LDS A row stride in halfwords (16B-aligned)
#define NTHR  256

typedef __attribute__((ext_vector_type(8)))  short bf16x8;   // 8 bf16 = 4 VGPRs
typedef __attribute__((ext_vector_type(16))) float f32x16;   // 32x32 accum

#define MFMA32(A, B, C) __builtin_amdgcn_mfma_f32_32x32x16_bf16(A, B, C, 0, 0, 0)

// ---------- pre-kernel: pack Wc1 into MFMA B-fragment order in d_ws ----------
// piece p = s*4 + nt (17*4 pieces, 1024 B each). lane l: n = nt*32 + (l&31),
// k = 16s + 8*(l>>5) + j, zero-padded past k=260.
__global__ void prep_B(const float* __restrict__ Wc1, uint16_t* __restrict__ wsB) {
    int t = blockIdx.x * blockDim.x + threadIdx.x;
    if (t >= NSTEP * 4 * 64) return;
    int p = t >> 6, l = t & 63;
    int s = p >> 2, nt = p & 3;
    int n = nt * 32 + (l & 31);
    int kb = 16 * s + 8 * (l >> 5);
    uint16_t hw[8];
    #pragma unroll
    for (int j = 0; j < 8; ++j) {
        int k = kb + j;
        float v = (k < FEATN) ? Wc1[(size_t)k * HIDN + n] : 0.f;
        __hip_bfloat16 b = __float2bfloat16(v);
        hw[j] = *reinterpret_cast<uint16_t*>(&b);
    }
    *reinterpret_cast<uint4*>(wsB + (size_t)p * 512 + l * 8) =
        *reinterpret_cast<uint4*>(hw);
}

// ---------- main fused kernel ----------
__global__ __launch_bounds__(NTHR, 3) void ac_fused(
    const float* __restrict__ x,
    const float* __restrict__ w0, const float* __restrict__ b0,
    const float* __restrict__ w1, const float* __restrict__ b1,
    const float* __restrict__ w2, const float* __restrict__ b2,
    const float* __restrict__ leaf,
    const uint16_t* __restrict__ wsB,
    const float* __restrict__ bc1, const float* __restrict__ Wc2,
    const float* __restrict__ bc2,
    float* __restrict__ out_p, float* __restrict__ out_v)
{
    __shared__ uint16_t Axs[ROWS * SROW];      // 37888 B, row-major bf16, k-contig
    __shared__ float bc1s[HIDN];
    __shared__ float wc2s[HIDN];
    __shared__ float vpart[ROWS * 2];

    const int tid = threadIdx.x;
    const int rowBase = blockIdx.x * ROWS;

    if (tid < HIDN) { bc1s[tid] = bc1[tid]; wc2s[tid] = Wc2[tid]; }
    // zero the k = 261..295 pad of each row
    if (tid < ROWS) {
        uint16_t* rp = Axs + tid * SROW;
        rp[261] = 0;
        *reinterpret_cast<uint32_t*>(rp + 262) = 0u;
        uint4 z; z.x = z.y = z.z = z.w = 0u;
        *reinterpret_cast<uint4*>(rp + 264) = z;
        *reinterpret_cast<uint4*>(rp + 272) = z;
        *reinterpret_cast<uint4*>(rp + 280) = z;
        *reinterpret_cast<uint4*>(rp + 288) = z;
    }

    // ---- phase 1a: coalesced float4 x read -> bf16 -> row-major LDS ----
    {
        const float4* xg4 = reinterpret_cast<const float4*>(x + (size_t)rowBase * FEATN);
        for (int i = tid; i < ROWS * FEATN / 4; i += NTHR) {
            float4 v = xg4[i];
            const float* vv = reinterpret_cast<const float*>(&v);
            int f = i << 2;
            int m = f / FEATN;          // magic-div
            int k = f - m * FEATN;
            if (k + 3 < FEATN) {        // fast path: single row
                uint16_t* dst = Axs + m * SROW + k;
                #pragma unroll
                for (int j = 0; j < 4; ++j) {
                    __hip_bfloat16 b = __float2bfloat16(vv[j]);
                    dst[j] = *reinterpret_cast<uint16_t*>(&b);
                }
            } else {
                #pragma unroll
                for (int j = 0; j < 4; ++j) {
                    if (k >= FEATN) { k -= FEATN; m++; }
                    __hip_bfloat16 b = __float2bfloat16(vv[j]);
                    Axs[m * SROW + k] = *reinterpret_cast<uint16_t*>(&b);
                    k++;
                }
            }
        }
    }

    // ---- phase 1b: tree (fp32). w0/w1 preloaded in registers; unmasked
    //      main loops, masked tails only; x loads are imm-offset batches. ----
    {
        const int s = tid & 15;

        float w0s[17];
        #pragma unroll
        for (int j = 0; j < 16; ++j) w0s[j] = w0[s + 16 * j];
        w0s[16] = (s < 5) ? w0[256 + s] : 0.f;

        float w1a[9], w1b[9];
        #pragma unroll
        for (int j = 0; j < 8; ++j) {
            w1a[j] = w1[s + 16 * j];
            w1b[j] = w1[133 + s + 16 * j];
        }
        w1a[8] = (s < 5) ? w1[128 + s]       : 0.f;
        w1b[8] = (s < 5) ? w1[133 + 128 + s] : 0.f;

        #pragma unroll
        for (int pass = 0; pass < 4; ++pass) {
            const int rloc = pass * 16 + (tid >> 4);
            const float* xr = x + (size_t)(rowBase + rloc) * FEATN;

            // level 0: 17 batched loads, then 17 FMA against preloaded w0
            float xv[17];
            #pragma unroll
            for (int j = 0; j < 16; ++j) xv[j] = xr[s + 16 * j];
            xv[16] = (s < 5) ? xr[256 + s] : 0.f;
            float part = 0.f;
            #pragma unroll
            for (int j = 0; j < 17; ++j) part += xv[j] * w0s[j];
            part += __shfl_xor(part, 1);
            part += __shfl_xor(part, 2);
            part += __shfl_xor(part, 4);
            part += __shfl_xor(part, 8);
            float gate = part + b0[0];
            int node = (gate >= 0.f) ? 1 : 0;
            float cum = 1.f / (1.f + __expf(-gate));

            // level 1: x from global (imm offsets), w1 from registers
            {
                const float* p = xr + node * 128 + s;   // x-idx = node*128 + t, t = s+16j
                float xw[9];
                xw[0] = (s < 5) ? xr[s] : p[0];
                #pragma unroll
                for (int j = 1; j < 8; ++j) xw[j] = p[16 * j];
                xw[8] = (s < 5) ? p[128] : 0.f;
                part = 0.f;
                #pragma unroll
                for (int j = 0; j < 9; ++j)
                    part += xw[j] * (node ? w1b[j] : w1a[j]);
                part += __shfl_xor(part, 1);
                part += __shfl_xor(part, 2);
                part += __shfl_xor(part, 4);
                part += __shfl_xor(part, 8);
                gate = part + b1[node];
                cum *= 1.f / (1.f + __expf(-gate));
                node = node * 2 + ((gate >= 0.f) ? 1 : 0);
            }
            // level 2: x + w2 from global (both imm-offset batches)
            {
                const float* w2r = w2 + node * 69;
                const float* p2  = xr + node * 64 + s;
                float xw[5], ww[5];
                xw[0] = (s < 5) ? xr[s] : p2[0];
                ww[0] = w2r[s];
                #pragma unroll
                for (int j = 1; j < 4; ++j) { xw[j] = p2[16 * j]; ww[j] = w2r[s + 16 * j]; }
                xw[4] = (s < 5) ? p2[64]      : 0.f;
                ww[4] = (s < 5) ? w2r[64 + s] : 0.f;
                part = 0.f;
                #pragma unroll
                for (int j = 0; j < 5; ++j) part += xw[j] * ww[j];
                part += __shfl_xor(part, 1);
                part += __shfl_xor(part, 2);
                part += __shfl_xor(part, 4);
                part += __shfl_xor(part, 8);
                gate = part + b2[node];
                cum *= 1.f / (1.f + __expf(-gate));
                node = node * 2 + ((gate >= 0.f) ? 1 : 0);
            }
            if (s < 8)
                out_p[(size_t)(rowBase + rloc) * 8 + s] = cum * leaf[node * 8 + s];
        }
    }

    __syncthreads();   // the only barrier before the K-loop

    // ---- phase 2: software-pipelined MFMA K-loop. A from LDS (b128),
    //      B from global frag-order; prefetch group g+1 while MFMA group g. ----
    const int lane = tid & 63;
    const int w    = tid >> 6;
    const int mt   = w >> 1;            // m-tile 0/1
    const int nh   = w & 1;             // n-tiles {2nh, 2nh+1}

    f32x16 acc0 = {}, acc1 = {};
    const uint16_t* arow = Axs + (mt * 32 + (lane & 31)) * SROW + (lane >> 5) * 8;
    const uint16_t* bgl  = wsB + (size_t)(2 * nh) * 512 + lane * 8;

    bf16x8 ca[4], cb0[4], cb1[4];
    bf16x8 na[4], nb0[4], nb1[4];
    #pragma unroll
    for (int d = 0; d < 4; ++d) {
        ca[d]  = *reinterpret_cast<const bf16x8*>(arow + d * 16);
        cb0[d] = *reinterpret_cast<const bf16x8*>(bgl + (size_t)(d * 4)     * 512);
        cb1[d] = *reinterpret_cast<const bf16x8*>(bgl + (size_t)(d * 4 + 1) * 512);
    }
    #pragma unroll
    for (int g = 0; g < 4; ++g) {
        if (g < 3) {
            #pragma unroll
            for (int d = 0; d < 4; ++d) {
                const int st = (g + 1) * 4 + d;
                na[d]  = *reinterpret_cast<const bf16x8*>(arow + st * 16);
                nb0[d] = *reinterpret_cast<const bf16x8*>(bgl + (size_t)(st * 4)     * 512);
                nb1[d] = *reinterpret_cast<const bf16x8*>(bgl + (size_t)(st * 4 + 1) * 512);
            }
        } else {
            na[0]  = *reinterpret_cast<const bf16x8*>(arow + 16 * 16);
            nb0[0] = *reinterpret_cast<const bf16x8*>(bgl + (size_t)(16 * 4)     * 512);
            nb1[0] = *reinterpret_cast<const bf16x8*>(bgl + (size_t)(16 * 4 + 1) * 512);
        }
        #pragma unroll
        for (int d = 0; d < 4; ++d) {
            acc0 = MFMA32(ca[d], cb0[d], acc0);
            acc1 = MFMA32(ca[d], cb1[d], acc1);
        }
        #pragma unroll
        for (int d = 0; d < 4; ++d) { ca[d] = na[d]; cb0[d] = nb0[d]; cb1[d] = nb1[d]; }
    }
    acc0 = MFMA32(ca[0], cb0[0], acc0);   // tail step s = 16
    acc1 = MFMA32(ca[0], cb1[0], acc1);

    // ---- epilogue: bias+relu+Wc2 dot, cross-lane reduce, v write ----
    {
        const int c = lane & 31;
        const int q = lane >> 5;
        const int n0 = 2 * nh * 32 + c;
        const int n1 = n0 + 32;
        const float bb0 = bc1s[n0], ww0 = wc2s[n0];
        const float bb1 = bc1s[n1], ww1 = wc2s[n1];

        float pv[16];
        #pragma unroll
        for (int reg = 0; reg < 16; ++reg) {
            float h0 = acc0[reg] + bb0; h0 = h0 > 0.f ? h0 : 0.f;
            float h1 = acc1[reg] + bb1; h1 = h1 > 0.f ? h1 : 0.f;
            float t = h0 * ww0 + h1 * ww1;
            t += __shfl_xor(t, 1);
            t += __shfl_xor(t, 2);
            t += __shfl_xor(t, 4);
            t += __shfl_xor(t, 8);
            t += __shfl_xor(t, 16);
            pv[reg] = t;
        }
        #pragma unroll
        for (int reg = 0; reg < 16; ++reg) {
            if (c == reg) {
                int row_local = (reg & 3) + 8 * (reg >> 2) + 4 * q;
                vpart[(mt * 32 + row_local) * 2 + nh] = pv[reg];
            }
        }
    }
    __syncthreads();
    if (tid < ROWS)
        out_v[rowBase + tid] = vpart[tid * 2] + vpart[tid * 2 + 1] + bc2[0];
}

extern "C" void kernel_launch(void* const* d_in, const int* in_sizes, int n_in,
                              void* d_out, int out_size, void* d_ws, size_t ws_size,
                              hipStream_t stream) {
    const float* x    = (const float*)d_in[0];
    const float* w0   = (const float*)d_in[1];
    const float* b0   = (const float*)d_in[2];
    const float* w1   = (const float*)d_in[3];
    const float* b1   = (const float*)d_in[4];
    const float* w2   = (const float*)d_in[5];
    const float* b2   = (const float*)d_in[6];
    const float* leaf = (const float*)d_in[7];
    const float* Wc1  = (const float*)d_in[8];
    const float* bc1  = (const float*)d_in[9];
    const float* Wc2  = (const float*)d_in[10];
    const float* bc2  = (const float*)d_in[11];

    uint16_t* wsB = (uint16_t*)d_ws;     // 17*4*1024 = 69632 B, frag order

    float* out_p = (float*)d_out;
    float* out_v = out_p + (size_t)NB * 8;

    prep_B<<<(NSTEP * 4 * 64 + 255) / 256, 256, 0, stream>>>(Wc1, wsB);
    ac_fused<<<NB / ROWS, NTHR, 0, stream>>>(
        x, w0, b0, w1, b1, w2, b2, leaf, wsB, bc1, Wc2, bc2, out_p, out_v);
}